// Round 2
// baseline (57131.726 us; speedup 1.0000x reference)
//
#include <hip/hip_runtime.h>
#include <math.h>

// Problem constants (fixed by setup_inputs)
#define NN 4096      // N samples
#define DD 256       // flat endo dim (8 vars * 32)
#define NV 8         // vars
#define VD 32        // per-var dim
#define NB 128       // GJ block size
#define NBLK (NN/NB) // 32

// ---------------- helpers ----------------
__device__ __forceinline__ void block_atomic_add(float v, float* red, float* dst){
  #pragma unroll
  for (int off = 32; off > 0; off >>= 1) v += __shfl_down(v, off, 64);
  const int lane = threadIdx.x & 63;
  const int w = threadIdx.x >> 6;
  if (lane == 0) red[w] = v;
  __syncthreads();
  if (threadIdx.x == 0) atomicAdd(dst, red[0] + red[1] + red[2] + red[3]);
  __syncthreads();
}

// ---------------- small utility kernels ----------------
__global__ void k_zero(float* p, int n){
  int i = blockIdx.x * blockDim.x + threadIdx.x;
  if (i < n) p[i] = 0.f;
}

// per-(row,var) sums/norms
__global__ void k_norms(const float* __restrict__ z, const float* __restrict__ zz,
                        const float* __restrict__ stdn,
                        float* __restrict__ stdsq, float* __restrict__ zrs,
                        float* __restrict__ nzz, float* __restrict__ nz8){
  int t = blockIdx.x * blockDim.x + threadIdx.x;
  if (t >= NN * NV) return;
  int i = t / NV, v = t % NV;
  const float* zp  = z  + (size_t)i * DD + v * VD;
  const float* zzp = zz + (size_t)i * DD + v * VD;
  float s1 = 0.f, s2 = 0.f, s2z = 0.f;
  #pragma unroll
  for (int k = 0; k < VD; k++){
    float a = zp[k];  s1 += a; s2 += a * a;
    float b = zzp[k]; s2z += b * b;
  }
  zrs[(size_t)i * NV + v] = s1;
  nz8[(size_t)v * NN + i] = s2;
  nzz[(size_t)v * NN + i] = s2z;
  if (v == 0){
    float s = 0.f;
    #pragma unroll
    for (int u = 0; u < NV; u++){ float a = stdn[(size_t)i * NV + u]; s += a * a; }
    stdsq[i] = s;
  }
}

__global__ void k_rownorm(const float* __restrict__ nz8, float* __restrict__ nrmz){
  int i = blockIdx.x * blockDim.x + threadIdx.x;
  if (i < NN){
    float s = 0.f;
    #pragma unroll
    for (int v = 0; v < NV; v++) s += nz8[(size_t)v * NN + i];
    nrmz[i] = s;
  }
}

__global__ __launch_bounds__(256) void k_nll(const float* __restrict__ x,
                                             const float* __restrict__ xx,
                                             float* __restrict__ slots){
  __shared__ float red[4];
  float s = 0.f;
  const int total = NN * DD;
  for (int i = (blockIdx.x * 256 + threadIdx.x) * 4; i < total; i += gridDim.x * 256 * 4){
    float4 a = *(const float4*)(x + i);
    float4 b = *(const float4*)(xx + i);
    float d0 = b.x - a.x, d1 = b.y - a.y, d2 = b.z - a.z, d3 = b.w - a.w;
    s += d0*d0 + d1*d1 + d2*d2 + d3*d3;
  }
  block_atomic_add(s, red, slots + 3);
}

// ---------------- first (exo-free) MMD term ----------------
// Sqq = sum_ij exp(-||z_i - z_j||^2 / 2048), flat dim 256
__global__ __launch_bounds__(256) void k_sqq(const float* __restrict__ z,
                                             const float* __restrict__ nrm,
                                             float* __restrict__ slots){
  __shared__ float Xr[128 * 33];
  __shared__ float Xc[128 * 33];
  __shared__ float red[4];
  const int r0 = blockIdx.y * 128, c0 = blockIdx.x * 128;
  const int t = threadIdx.x;
  const int tx = t & 15, ty = t >> 4;
  const int lrow = t >> 1, lh = t & 1;
  float acc[8][8];
  #pragma unroll
  for (int u = 0; u < 8; u++)
    #pragma unroll
    for (int v = 0; v < 8; v++) acc[u][v] = 0.f;
  for (int ks = 0; ks < DD; ks += 32){
    const float* pr = z + (size_t)(r0 + lrow) * DD + ks + lh * 16;
    const float* pc = z + (size_t)(c0 + lrow) * DD + ks + lh * 16;
    float* dr = &Xr[lrow * 33 + lh * 16];
    float* dc = &Xc[lrow * 33 + lh * 16];
    #pragma unroll
    for (int u = 0; u < 4; u++){
      float4 a = ((const float4*)pr)[u];
      dr[4*u+0] = a.x; dr[4*u+1] = a.y; dr[4*u+2] = a.z; dr[4*u+3] = a.w;
      float4 b = ((const float4*)pc)[u];
      dc[4*u+0] = b.x; dc[4*u+1] = b.y; dc[4*u+2] = b.z; dc[4*u+3] = b.w;
    }
    __syncthreads();
    #pragma unroll
    for (int kk = 0; kk < 32; kk++){
      float a[8], b[8];
      #pragma unroll
      for (int u = 0; u < 8; u++) a[u] = Xr[(ty*8+u)*33 + kk];
      #pragma unroll
      for (int v = 0; v < 8; v++) b[v] = Xc[(tx*8+v)*33 + kk];
      #pragma unroll
      for (int u = 0; u < 8; u++)
        #pragma unroll
        for (int v = 0; v < 8; v++) acc[u][v] += a[u] * b[v];
    }
    __syncthreads();
  }
  float s = 0.f;
  #pragma unroll 1
  for (int u = 0; u < 8; u++){
    const float ni = nrm[r0 + ty*8 + u];
    #pragma unroll 1
    for (int v = 0; v < 8; v++)
      s += __expf(-(ni + nrm[c0 + tx*8 + v] - 2.f * acc[u][v]) * (1.f/2048.f));
  }
  block_atomic_add(s, red, slots + 0);
}

// Spp and Sqp via K=8 structure of the broadcast std_norm
__global__ __launch_bounds__(256) void k_spp_sqp(const float* __restrict__ stdn,
                                                 const float* __restrict__ stdsq,
                                                 const float* __restrict__ zrs,
                                                 const float* __restrict__ nrmz,
                                                 float* __restrict__ slots){
  __shared__ float sI[128*9], sJ[128*9], zI[128*9];
  __shared__ float qI[128], qJ[128], nI[128];
  __shared__ float red[4];
  const int r0 = blockIdx.y * 128, c0 = blockIdx.x * 128;
  const int t = threadIdx.x;
  if (t < 128){
    #pragma unroll
    for (int v = 0; v < 8; v++){
      sI[t*9+v] = stdn[(size_t)(r0+t)*NV + v];
      sJ[t*9+v] = stdn[(size_t)(c0+t)*NV + v];
      zI[t*9+v] = zrs[(size_t)(r0+t)*NV + v];
    }
    qI[t] = stdsq[r0+t]; qJ[t] = stdsq[c0+t]; nI[t] = nrmz[r0+t];
  }
  __syncthreads();
  const int tx = t & 15, ty = t >> 4;
  float spp = 0.f, sqp = 0.f;
  #pragma unroll 1
  for (int u = 0; u < 8; u++){
    int i = ty*8 + u;
    #pragma unroll 1
    for (int v = 0; v < 8; v++){
      int j = tx*8 + v;
      float dpp = 0.f, dqp = 0.f;
      #pragma unroll
      for (int k = 0; k < 8; k++){
        float sj = sJ[j*9+k];
        dpp += sI[i*9+k] * sj;
        dqp += zI[i*9+k] * sj;
      }
      spp += __expf(-(qI[i] + qJ[j] - 2.f*dpp) * (1.f/64.f));
      sqp += __expf(-(nI[i] + 32.f*qJ[j] - 2.f*dqp) * (1.f/2048.f));
    }
  }
  block_atomic_add(spp, red, slots + 1);
  block_atomic_add(sqp, red, slots + 2);
}

// ---------------- RBF Gram matrix build (K=32) ----------------
// M[i][j] = exp(-(nr[i]+nc[j]-2*xr_i.xc_j)/32) + lam*(i==j)
__global__ __launch_bounds__(256) void k_rbf(const float* __restrict__ Xr_,
                                             const float* __restrict__ Xc_,
                                             const float* __restrict__ nr,
                                             const float* __restrict__ nc,
                                             float lam, float* __restrict__ M){
  __shared__ float Xr[128 * 33];
  __shared__ float Xc[128 * 33];
  const int r0 = blockIdx.y * 128, c0 = blockIdx.x * 128;
  const int t = threadIdx.x;
  const int tx = t & 15, ty = t >> 4;
  const int lrow = t >> 1, lh = t & 1;
  {
    const float* pr = Xr_ + (size_t)(r0 + lrow) * DD + lh * 16;
    const float* pc = Xc_ + (size_t)(c0 + lrow) * DD + lh * 16;
    float* dr = &Xr[lrow * 33 + lh * 16];
    float* dc = &Xc[lrow * 33 + lh * 16];
    #pragma unroll
    for (int u = 0; u < 4; u++){
      float4 a = ((const float4*)pr)[u];
      dr[4*u+0]=a.x; dr[4*u+1]=a.y; dr[4*u+2]=a.z; dr[4*u+3]=a.w;
      float4 b = ((const float4*)pc)[u];
      dc[4*u+0]=b.x; dc[4*u+1]=b.y; dc[4*u+2]=b.z; dc[4*u+3]=b.w;
    }
  }
  __syncthreads();
  #pragma unroll 1
  for (int u = 0; u < 8; u++){
    const int gi = r0 + ty*8 + u;
    const float* xi = &Xr[(ty*8+u)*33];
    const float ni = nr[gi];
    float vals[8];
    #pragma unroll 1
    for (int v = 0; v < 8; v++){
      const int gj = c0 + tx*8 + v;
      const float* xj = &Xc[(tx*8+v)*33];
      float d = 0.f;
      #pragma unroll
      for (int k = 0; k < 32; k++) d += xi[k] * xj[k];
      float e = __expf(-(ni + nc[gj] - 2.f*d) * (1.f/32.f));
      if (gi == gj) e += lam;
      vals[v] = e;
    }
    float* pd = M + (size_t)gi * NN + c0 + tx*8;
    ((float4*)pd)[0] = make_float4(vals[0], vals[1], vals[2], vals[3]);
    ((float4*)pd)[1] = make_float4(vals[4], vals[5], vals[6], vals[7]);
  }
}

// ---------------- elementwise trace reduction: sum(L (on-the-fly) * M) ----------------
__global__ __launch_bounds__(256) void k_reduce(const float* __restrict__ M, int nepi,
    const float* e0xr, const float* e0xc, const float* e0nr, const float* e0nc, int s0,
    const float* e1xr, const float* e1xc, const float* e1nr, const float* e1nc, int s1,
    float* __restrict__ slots){
  __shared__ float sh[128 * 33 * 2];
  __shared__ float red[4];
  const int r0 = blockIdx.y * 128, c0 = blockIdx.x * 128;
  const int t = threadIdx.x;
  const int tx = t & 15, ty = t >> 4;
  const int lrow = t >> 1, lh = t & 1;
  float macc[8][8];
  #pragma unroll
  for (int u = 0; u < 8; u++){
    const float* pm = M + (size_t)(r0 + ty*8 + u) * NN + c0 + tx*8;
    float4 m0 = ((const float4*)pm)[0], m1 = ((const float4*)pm)[1];
    macc[u][0]=m0.x; macc[u][1]=m0.y; macc[u][2]=m0.z; macc[u][3]=m0.w;
    macc[u][4]=m1.x; macc[u][5]=m1.y; macc[u][6]=m1.z; macc[u][7]=m1.w;
  }
  float* Xr = sh;
  float* Xc = sh + 128 * 33;
  for (int e = 0; e < nepi; e++){
    const float* xr = e ? e1xr : e0xr;
    const float* xc = e ? e1xc : e0xc;
    const float* nr = e ? e1nr : e0nr;
    const float* nc = e ? e1nc : e0nc;
    int slot = e ? s1 : s0;
    {
      const float* pr = xr + (size_t)(r0 + lrow) * DD + lh * 16;
      const float* pc = xc + (size_t)(c0 + lrow) * DD + lh * 16;
      float* dr = &Xr[lrow * 33 + lh * 16];
      float* dc = &Xc[lrow * 33 + lh * 16];
      #pragma unroll
      for (int u = 0; u < 4; u++){
        float4 a = ((const float4*)pr)[u];
        dr[4*u+0]=a.x; dr[4*u+1]=a.y; dr[4*u+2]=a.z; dr[4*u+3]=a.w;
        float4 b = ((const float4*)pc)[u];
        dc[4*u+0]=b.x; dc[4*u+1]=b.y; dc[4*u+2]=b.z; dc[4*u+3]=b.w;
      }
    }
    __syncthreads();
    float s = 0.f;
    #pragma unroll 1
    for (int u = 0; u < 8; u++){
      const float* xi = &Xr[(ty*8+u)*33];
      const float ni = nr[r0 + ty*8 + u];
      #pragma unroll 1
      for (int v = 0; v < 8; v++){
        const float* xj = &Xc[(tx*8+v)*33];
        float d = 0.f;
        #pragma unroll
        for (int k = 0; k < 32; k++) d += xi[k] * xj[k];
        s += macc[u][v] * __expf(-(ni + nc[c0 + tx*8 + v] - 2.f*d) * (1.f/32.f));
      }
    }
    block_atomic_add(s, red, slots + slot);
    __syncthreads();
  }
}

// ---------------- big fp32 GEMM, optional store, optional fused RBF-trace epilogues ----------------
__global__ __launch_bounds__(256) void k_gemm(const float* __restrict__ A,
                                              const float* __restrict__ B,
                                              float* __restrict__ D, int storeD, int nepi,
    const float* e0xr, const float* e0xc, const float* e0nr, const float* e0nc, int s0,
    const float* e1xr, const float* e1xc, const float* e1nr, const float* e1nc, int s1,
    float* __restrict__ slots){
  __shared__ float sh[128 * 33 * 2];
  __shared__ float red[4];
  const int r0 = blockIdx.y * 128, c0 = blockIdx.x * 128;
  const int t = threadIdx.x;
  const int tx = t & 15, ty = t >> 4;
  const int lrow = t >> 1, lh = t & 1;
  float acc[8][8];
  #pragma unroll
  for (int u = 0; u < 8; u++)
    #pragma unroll
    for (int v = 0; v < 8; v++) acc[u][v] = 0.f;

  float* As = sh;            // [128][17]
  float* Bs = sh + 128 * 17; // [128][17]
  for (int ks = 0; ks < NN; ks += 16){
    {
      const float* pa = A + (size_t)(r0 + lrow) * NN + ks + lh * 8;
      float4 a0 = ((const float4*)pa)[0];
      float4 a1 = ((const float4*)pa)[1];
      float* da = &As[lrow * 17 + lh * 8];
      da[0]=a0.x; da[1]=a0.y; da[2]=a0.z; da[3]=a0.w;
      da[4]=a1.x; da[5]=a1.y; da[6]=a1.z; da[7]=a1.w;
      const int kkl = t >> 4, c8 = (t & 15) * 8;
      const float* pb = B + (size_t)(ks + kkl) * NN + c0 + c8;
      float4 b0 = ((const float4*)pb)[0];
      float4 b1 = ((const float4*)pb)[1];
      Bs[(c8+0)*17+kkl]=b0.x; Bs[(c8+1)*17+kkl]=b0.y; Bs[(c8+2)*17+kkl]=b0.z; Bs[(c8+3)*17+kkl]=b0.w;
      Bs[(c8+4)*17+kkl]=b1.x; Bs[(c8+5)*17+kkl]=b1.y; Bs[(c8+6)*17+kkl]=b1.z; Bs[(c8+7)*17+kkl]=b1.w;
    }
    __syncthreads();
    #pragma unroll
    for (int kk = 0; kk < 16; kk++){
      float a[8], b[8];
      #pragma unroll
      for (int u = 0; u < 8; u++) a[u] = As[(ty*8+u)*17 + kk];
      #pragma unroll
      for (int v = 0; v < 8; v++) b[v] = Bs[(tx*8+v)*17 + kk];
      #pragma unroll
      for (int u = 0; u < 8; u++)
        #pragma unroll
        for (int v = 0; v < 8; v++) acc[u][v] += a[u] * b[v];
    }
    __syncthreads();
  }
  if (storeD){
    #pragma unroll
    for (int u = 0; u < 8; u++){
      float* pd = D + (size_t)(r0 + ty*8 + u) * NN + c0 + tx*8;
      ((float4*)pd)[0] = make_float4(acc[u][0], acc[u][1], acc[u][2], acc[u][3]);
      ((float4*)pd)[1] = make_float4(acc[u][4], acc[u][5], acc[u][6], acc[u][7]);
    }
  }
  float* Xr = sh;
  float* Xc = sh + 128 * 33;
  for (int e = 0; e < nepi; e++){
    const float* xr = e ? e1xr : e0xr;
    const float* xc = e ? e1xc : e0xc;
    const float* nr = e ? e1nr : e0nr;
    const float* nc = e ? e1nc : e0nc;
    int slot = e ? s1 : s0;
    {
      const float* pr = xr + (size_t)(r0 + lrow) * DD + lh * 16;
      const float* pc = xc + (size_t)(c0 + lrow) * DD + lh * 16;
      float* dr = &Xr[lrow * 33 + lh * 16];
      float* dc = &Xc[lrow * 33 + lh * 16];
      #pragma unroll
      for (int u = 0; u < 4; u++){
        float4 a = ((const float4*)pr)[u];
        dr[4*u+0]=a.x; dr[4*u+1]=a.y; dr[4*u+2]=a.z; dr[4*u+3]=a.w;
        float4 b = ((const float4*)pc)[u];
        dc[4*u+0]=b.x; dc[4*u+1]=b.y; dc[4*u+2]=b.z; dc[4*u+3]=b.w;
      }
    }
    __syncthreads();
    float s = 0.f;
    #pragma unroll 1
    for (int u = 0; u < 8; u++){
      const float* xi = &Xr[(ty*8+u)*33];
      const float ni = nr[r0 + ty*8 + u];
      #pragma unroll 1
      for (int v = 0; v < 8; v++){
        const float* xj = &Xc[(tx*8+v)*33];
        float d = 0.f;
        #pragma unroll
        for (int k = 0; k < 32; k++) d += xi[k] * xj[k];
        s += acc[u][v] * __expf(-(ni + nc[c0 + tx*8 + v] - 2.f*d) * (1.f/32.f));
      }
    }
    block_atomic_add(s, red, slots + slot);
    __syncthreads();
  }
}

// ---------------- U = Kqp(on-the-fly) @ B  (saves materializing Kqp) ----------------
// Kqp[i,l] = exp(-(nq[i]+np[l]-2*q_i.p_l)/32); rows i = Xq samples, k-index l = Xp samples.
__global__ __launch_bounds__(256) void k_gemm_kqpB(
    const float* __restrict__ Xq, const float* __restrict__ nq,
    const float* __restrict__ Xp, const float* __restrict__ np_,
    const float* __restrict__ B, float* __restrict__ U){
  __shared__ float Q[128 * 33];   // row-side exo vectors (loaded once)
  __shared__ float Zk[16 * 33];   // k-side exo vectors for current k block
  __shared__ float As[128 * 17];  // generated Kqp tile
  __shared__ float Bs[128 * 17];
  const int r0 = blockIdx.y * 128, c0 = blockIdx.x * 128;
  const int t = threadIdx.x;
  const int tx = t & 15, ty = t >> 4;
  const int lrow = t >> 1, lh = t & 1;
  {
    const float* pr = Xq + (size_t)(r0 + lrow) * DD + lh * 16;
    float* dr = &Q[lrow * 33 + lh * 16];
    #pragma unroll
    for (int u = 0; u < 4; u++){
      float4 a = ((const float4*)pr)[u];
      dr[4*u+0]=a.x; dr[4*u+1]=a.y; dr[4*u+2]=a.z; dr[4*u+3]=a.w;
    }
  }
  const int arow = t >> 1, acb = (t & 1) * 8;   // A-tile generation assignment
  const float nqr = nq[r0 + arow];
  float acc[8][8];
  #pragma unroll
  for (int u = 0; u < 8; u++)
    #pragma unroll
    for (int v = 0; v < 8; v++) acc[u][v] = 0.f;
  for (int ks = 0; ks < NN; ks += 16){
    // load Zk (16 x 32) and B tile
    if (t < 128){
      const int zr = t >> 3, zs = (t & 7) * 4;
      float4 a = *(const float4*)(Xp + (size_t)(ks + zr) * DD + zs);
      float* d = &Zk[zr * 33 + zs];
      d[0]=a.x; d[1]=a.y; d[2]=a.z; d[3]=a.w;
    }
    {
      const int kkl = t >> 4, c8 = (t & 15) * 8;
      const float* pb = B + (size_t)(ks + kkl) * NN + c0 + c8;
      float4 b0 = ((const float4*)pb)[0];
      float4 b1 = ((const float4*)pb)[1];
      Bs[(c8+0)*17+kkl]=b0.x; Bs[(c8+1)*17+kkl]=b0.y; Bs[(c8+2)*17+kkl]=b0.z; Bs[(c8+3)*17+kkl]=b0.w;
      Bs[(c8+4)*17+kkl]=b1.x; Bs[(c8+5)*17+kkl]=b1.y; Bs[(c8+6)*17+kkl]=b1.z; Bs[(c8+7)*17+kkl]=b1.w;
    }
    __syncthreads();
    // generate Kqp tile: thread -> row arow, k-cols acb..acb+7
    {
      const float* qi = &Q[arow * 33];
      #pragma unroll
      for (int j = 0; j < 8; j++){
        const int c = acb + j;
        const float* pj = &Zk[c * 33];
        float d = 0.f;
        #pragma unroll
        for (int k = 0; k < 32; k++) d += qi[k] * pj[k];
        As[arow * 17 + c] = __expf(-(nqr + np_[ks + c] - 2.f*d) * (1.f/32.f));
      }
    }
    __syncthreads();
    #pragma unroll
    for (int kk = 0; kk < 16; kk++){
      float a[8], b[8];
      #pragma unroll
      for (int u = 0; u < 8; u++) a[u] = As[(ty*8+u)*17 + kk];
      #pragma unroll
      for (int v = 0; v < 8; v++) b[v] = Bs[(tx*8+v)*17 + kk];
      #pragma unroll
      for (int u = 0; u < 8; u++)
        #pragma unroll
        for (int v = 0; v < 8; v++) acc[u][v] += a[u] * b[v];
    }
    __syncthreads();
  }
  #pragma unroll
  for (int u = 0; u < 8; u++){
    float* pd = U + (size_t)(r0 + ty*8 + u) * NN + c0 + tx*8;
    ((float4*)pd)[0] = make_float4(acc[u][0], acc[u][1], acc[u][2], acc[u][3]);
    ((float4*)pd)[1] = make_float4(acc[u][4], acc[u][5], acc[u][6], acc[u][7]);
  }
}

// ---------------- blocked Gauss-Jordan SPD inverse (batched x2 via blockIdx) ----------------
// Diag block 128x128 inverse, register-resident, one WG of 1024 threads per matrix.
__global__ __launch_bounds__(1024) void k_gj_diag(float* __restrict__ M0, float* __restrict__ M1,
                                                  float* __restrict__ Pbuf, int kb){
  float* M = blockIdx.x ? M1 : M0;
  float* P = Pbuf + (size_t)blockIdx.x * NB * NB;
  __shared__ float rowbuf[NB];
  __shared__ float colbuf[NB];
  __shared__ float pivsh;
  const int t = threadIdx.x;
  const int r = t >> 3, g = t & 7;   // row 0..127, col-group 0..7 (cols g+8j)
  const int k0 = kb * NB;
  float reg[16];
  #pragma unroll
  for (int j = 0; j < 16; j++) reg[j] = M[(size_t)(k0 + r) * NN + k0 + g + 8*j];
  __syncthreads();
  for (int jj = 0; jj < NB; jj++){
    if (r == jj && g == (jj & 7)) pivsh = reg[jj >> 3];
    __syncthreads();
    const float p = 1.0f / pivsh;
    if (r == jj){
      #pragma unroll
      for (int j = 0; j < 16; j++){
        int c = g + 8*j;
        float val = (c == jj) ? p : reg[j] * p;
        reg[j] = val;
        rowbuf[c] = val;
      }
    } else if (g == (jj & 7)){
      colbuf[r] = reg[jj >> 3];
    }
    __syncthreads();
    if (r != jj){
      const float f = colbuf[r];
      #pragma unroll
      for (int j = 0; j < 16; j++){
        int c = g + 8*j;
        reg[j] = (c == jj) ? (-f * p) : (reg[j] - f * rowbuf[c]);
      }
    }
    __syncthreads();
  }
  #pragma unroll
  for (int j = 0; j < 16; j++) P[r * NB + g + 8*j] = reg[j];
}

// Panel: T = P @ M[k-block row, :]; C = copy of M[:, k-block col]
__global__ __launch_bounds__(256) void k_gj_panel(float* __restrict__ M0, float* __restrict__ M1,
                                                  const float* __restrict__ Pbuf,
                                                  float* __restrict__ Tbuf, float* __restrict__ Cbuf,
                                                  int kb){
  const int mat = blockIdx.y;
  float* M = mat ? M1 : M0;
  const float* P = Pbuf + (size_t)mat * NB * NB;
  float* T = Tbuf + (size_t)mat * NB * NN;
  float* C = Cbuf + (size_t)mat * NN * NB;
  const int jb = blockIdx.x;
  const int k0 = kb * NB, j0 = jb * NB;
  const int t = threadIdx.x;
  // C copy (old column panel, rows j0..)
  {
    const int row = t >> 1, half = (t & 1) * 64;
    const float* src = M + (size_t)(j0 + row) * NN + k0 + half;
    float* dst = C + (size_t)(j0 + row) * NB + half;
    #pragma unroll
    for (int u = 0; u < 16; u++) ((float4*)dst)[u] = ((const float4*)src)[u];
  }
  __shared__ float As[128 * 17];
  __shared__ float Bs[128 * 17];
  const int tx = t & 15, ty = t >> 4;
  const int lrow = t >> 1, lh = t & 1;
  float acc[8][8];
  #pragma unroll
  for (int u = 0; u < 8; u++)
    #pragma unroll
    for (int v = 0; v < 8; v++) acc[u][v] = 0.f;
  for (int ks = 0; ks < NB; ks += 16){
    {
      const float* pa = P + (size_t)lrow * NB + ks + lh * 8;
      float4 a0 = ((const float4*)pa)[0];
      float4 a1 = ((const float4*)pa)[1];
      float* da = &As[lrow * 17 + lh * 8];
      da[0]=a0.x; da[1]=a0.y; da[2]=a0.z; da[3]=a0.w;
      da[4]=a1.x; da[5]=a1.y; da[6]=a1.z; da[7]=a1.w;
      const int kkl = t >> 4, c8 = (t & 15) * 8;
      const float* pb = M + (size_t)(k0 + ks + kkl) * NN + j0 + c8;
      float4 b0 = ((const float4*)pb)[0];
      float4 b1 = ((const float4*)pb)[1];
      Bs[(c8+0)*17+kkl]=b0.x; Bs[(c8+1)*17+kkl]=b0.y; Bs[(c8+2)*17+kkl]=b0.z; Bs[(c8+3)*17+kkl]=b0.w;
      Bs[(c8+4)*17+kkl]=b1.x; Bs[(c8+5)*17+kkl]=b1.y; Bs[(c8+6)*17+kkl]=b1.z; Bs[(c8+7)*17+kkl]=b1.w;
    }
    __syncthreads();
    #pragma unroll
    for (int kk = 0; kk < 16; kk++){
      float a[8], b[8];
      #pragma unroll
      for (int u = 0; u < 8; u++) a[u] = As[(ty*8+u)*17 + kk];
      #pragma unroll
      for (int v = 0; v < 8; v++) b[v] = Bs[(tx*8+v)*17 + kk];
      #pragma unroll
      for (int u = 0; u < 8; u++)
        #pragma unroll
        for (int v = 0; v < 8; v++) acc[u][v] += a[u] * b[v];
    }
    __syncthreads();
  }
  #pragma unroll
  for (int u = 0; u < 8; u++){
    float* pd = T + (size_t)(ty*8 + u) * NN + j0 + tx*8;
    ((float4*)pd)[0] = make_float4(acc[u][0], acc[u][1], acc[u][2], acc[u][3]);
    ((float4*)pd)[1] = make_float4(acc[u][4], acc[u][5], acc[u][6], acc[u][7]);
  }
}

// Trailing update + panel writeback
__global__ __launch_bounds__(256) void k_gj_update(float* __restrict__ M0, float* __restrict__ M1,
                                                   const float* __restrict__ Pbuf,
                                                   const float* __restrict__ Tbuf,
                                                   const float* __restrict__ Cbuf, int kb){
  __shared__ float As[128 * 17];
  __shared__ float Bs[128 * 17];
  const int mat = blockIdx.z;
  float* M = mat ? M1 : M0;
  const float* P = Pbuf + (size_t)mat * NB * NB;
  const float* T = Tbuf + (size_t)mat * NB * NN;
  const float* C = Cbuf + (size_t)mat * NN * NB;
  const int jb = blockIdx.x, ib = blockIdx.y;
  const int k0 = kb * NB, i0 = ib * NB, j0 = jb * NB;
  const int t = threadIdx.x;
  if (ib == kb){
    const int row = t >> 1, half = (t & 1) * 64;
    float* dst = M + (size_t)(k0 + row) * NN + j0 + half;
    if (jb == kb){
      const float* src = P + (size_t)row * NB + half;
      #pragma unroll
      for (int u = 0; u < 16; u++) ((float4*)dst)[u] = ((const float4*)src)[u];
    } else {
      const float* src = T + (size_t)row * NN + j0 + half;
      #pragma unroll
      for (int u = 0; u < 16; u++) ((float4*)dst)[u] = ((const float4*)src)[u];
    }
    return;
  }
  const int tx = t & 15, ty = t >> 4;
  const int lrow = t >> 1, lh = t & 1;
  float acc[8][8];
  #pragma unroll
  for (int u = 0; u < 8; u++)
    #pragma unroll
    for (int v = 0; v < 8; v++) acc[u][v] = 0.f;
  const float* Bbase = (jb == kb) ? P : (T + j0);
  const size_t ldb = (jb == kb) ? (size_t)NB : (size_t)NN;
  for (int ks = 0; ks < NB; ks += 16){
    {
      const float* pa = C + (size_t)(i0 + lrow) * NB + ks + lh * 8;
      float4 a0 = ((const float4*)pa)[0];
      float4 a1 = ((const float4*)pa)[1];
      float* da = &As[lrow * 17 + lh * 8];
      da[0]=a0.x; da[1]=a0.y; da[2]=a0.z; da[3]=a0.w;
      da[4]=a1.x; da[5]=a1.y; da[6]=a1.z; da[7]=a1.w;
      const int kkl = t >> 4, c8 = (t & 15) * 8;
      const float* pb = Bbase + (size_t)(ks + kkl) * ldb + c8;
      float4 b0 = ((const float4*)pb)[0];
      float4 b1 = ((const float4*)pb)[1];
      Bs[(c8+0)*17+kkl]=b0.x; Bs[(c8+1)*17+kkl]=b0.y; Bs[(c8+2)*17+kkl]=b0.z; Bs[(c8+3)*17+kkl]=b0.w;
      Bs[(c8+4)*17+kkl]=b1.x; Bs[(c8+5)*17+kkl]=b1.y; Bs[(c8+6)*17+kkl]=b1.z; Bs[(c8+7)*17+kkl]=b1.w;
    }
    __syncthreads();
    #pragma unroll
    for (int kk = 0; kk < 16; kk++){
      float a[8], b[8];
      #pragma unroll
      for (int u = 0; u < 8; u++) a[u] = As[(ty*8+u)*17 + kk];
      #pragma unroll
      for (int v = 0; v < 8; v++) b[v] = Bs[(tx*8+v)*17 + kk];
      #pragma unroll
      for (int u = 0; u < 8; u++)
        #pragma unroll
        for (int v = 0; v < 8; v++) acc[u][v] += a[u] * b[v];
    }
    __syncthreads();
  }
  if (jb == kb){
    #pragma unroll
    for (int u = 0; u < 8; u++){
      float* pd = M + (size_t)(i0 + ty*8 + u) * NN + k0 + tx*8;
      ((float4*)pd)[0] = make_float4(-acc[u][0], -acc[u][1], -acc[u][2], -acc[u][3]);
      ((float4*)pd)[1] = make_float4(-acc[u][4], -acc[u][5], -acc[u][6], -acc[u][7]);
    }
  } else {
    #pragma unroll
    for (int u = 0; u < 8; u++){
      float* pd = M + (size_t)(i0 + ty*8 + u) * NN + j0 + tx*8;
      float4 m0 = ((const float4*)pd)[0], m1 = ((const float4*)pd)[1];
      m0.x -= acc[u][0]; m0.y -= acc[u][1]; m0.z -= acc[u][2]; m0.w -= acc[u][3];
      m1.x -= acc[u][4]; m1.y -= acc[u][5]; m1.z -= acc[u][6]; m1.w -= acc[u][7];
      ((float4*)pd)[0] = m0; ((float4*)pd)[1] = m1;
    }
  }
}

// ---------------- final combine ----------------
__global__ void k_combine(const float* __restrict__ slots, float* __restrict__ out){
  if (threadIdx.x == 0 && blockIdx.x == 0){
    const double invN2 = 1.0 / ((double)NN * (double)NN);
    double term1 = ((double)slots[0] + (double)slots[1] - 2.0 * (double)slots[2]) * invN2;
    double pairs = 0.0;
    for (int p = 0; p < 3; p++){
      const float* s = slots + 4 + 5 * p;
      pairs += ((double)s[0] - 0.2 * (double)s[1] + (double)s[2] - 0.2 * (double)s[3] - 2.0 * (double)s[4]);
    }
    out[0] = (float)(1.0 * term1 + 500.0 * pairs * invN2);
    out[1] = (float)((double)slots[3] / (2.0 * (double)NN));
  }
}

// ---------------- host ----------------
extern "C" void kernel_launch(void* const* d_in, const int* in_sizes, int n_in,
                              void* d_out, int out_size, void* d_ws, size_t ws_size,
                              hipStream_t stream){
  const float* x    = (const float*)d_in[0];
  const float* z    = (const float*)d_in[1];
  const float* zz   = (const float*)d_in[2];
  const float* xx   = (const float*)d_in[3];
  const float* stdn = (const float*)d_in[4];
  float* out = (float*)d_out;
  float* ws  = (float*)d_ws;

  const size_t NN2 = (size_t)NN * NN;
  // 3 big buffers + panels + aux: ~200.6 MiB total
  float* bufA = ws;                       // Kq -> A = Kq^-1
  float* bufB = bufA + NN2;               // Kp -> B = Kp^-1
  float* bufT = bufB + NN2;               // U = Kqp @ B (Kqp generated on the fly)
  float* Tb   = bufT + NN2;               // 2 * NB * NN
  float* Cb   = Tb + 2 * (size_t)NB * NN; // 2 * NN * NB
  float* Pb   = Cb + 2 * (size_t)NB * NN; // 2 * NB * NB
  float* slots= Pb + 2 * (size_t)NB * NB; // 32
  float* stdsq= slots + 32;               // NN
  float* zrs  = stdsq + NN;               // NN*NV
  float* nzz  = zrs + (size_t)NN * NV;    // NV*NN (zz per-var sq norms)
  float* nz8  = nzz + (size_t)NV * NN;    // NV*NN (z per-var sq norms)
  float* nrmz = nz8 + (size_t)NV * NN;    // NN (z flat-256 sq norms)

  dim3 g32(NBLK, NBLK);

  k_zero<<<1, 64, 0, stream>>>(slots, 32);
  k_norms<<<(NN * NV) / 256, 256, 0, stream>>>(z, zz, stdn, stdsq, zrs, nzz, nz8);
  k_rownorm<<<NN / 256, 256, 0, stream>>>(nz8, nrmz);
  k_nll<<<1024, 256, 0, stream>>>(x, xx, slots);
  k_sqq<<<g32, 256, 0, stream>>>(z, nrmz, slots);
  k_spp_sqp<<<g32, 256, 0, stream>>>(stdn, stdsq, zrs, nrmz, slots);

  const float* zz0 = zz;            const float* z0 = z;
  const float* zz1 = zz + VD;       const float* z1 = z + VD;
  const float* nzz0 = nzz;          const float* nz0 = nz8;
  const float* nzz1 = nzz + NN;     const float* nz1 = nz8 + NN;

  for (int b = 1; b <= 2; b++){
    // Build Kq (zz var b) and Kp (z var b) with +0.2 I, then invert both in place.
    k_rbf<<<g32, 256, 0, stream>>>(zz + b*VD, zz + b*VD, nzz + (size_t)b*NN, nzz + (size_t)b*NN, 0.2f, bufA);
    k_rbf<<<g32, 256, 0, stream>>>(z + b*VD,  z + b*VD,  nz8 + (size_t)b*NN, nz8 + (size_t)b*NN, 0.2f, bufB);
    for (int kb = 0; kb < NBLK; kb++){
      k_gj_diag<<<2, 1024, 0, stream>>>(bufA, bufB, Pb, kb);
      k_gj_panel<<<dim3(NBLK, 2), 256, 0, stream>>>(bufA, bufB, Pb, Tb, Cb, kb);
      k_gj_update<<<dim3(NBLK, NBLK, 2), 256, 0, stream>>>(bufA, bufB, Pb, Tb, Cb, kb);
    }
    // U = Kqp @ B with Kqp generated on the fly (rows: zz_b, k-dim: z_b)
    k_gemm_kqpB<<<g32, 256, 0, stream>>>(zz + b*VD, nzz + (size_t)b*NN,
                                         z + b*VD,  nz8 + (size_t)b*NN, bufB, bufT);
    if (b == 1){
      // pair p=0: endo a=0
      k_reduce<<<g32, 256, 0, stream>>>(bufA, 1, zz0, zz0, nzz0, nzz0, 4,
                                        nullptr, nullptr, nullptr, nullptr, 0, slots);
      k_reduce<<<g32, 256, 0, stream>>>(bufB, 1, z0, z0, nz0, nz0, 6,
                                        nullptr, nullptr, nullptr, nullptr, 0, slots);
      k_gemm<<<g32, 256, 0, stream>>>(bufA, bufA, nullptr, 0, 1,
                                      zz0, zz0, nzz0, nzz0, 5,
                                      nullptr, nullptr, nullptr, nullptr, 0, slots);
      k_gemm<<<g32, 256, 0, stream>>>(bufB, bufB, nullptr, 0, 1,
                                      z0, z0, nz0, nz0, 7,
                                      nullptr, nullptr, nullptr, nullptr, 0, slots);
      k_gemm<<<g32, 256, 0, stream>>>(bufA, bufT, nullptr, 0, 1,
                                      zz0, z0, nzz0, nz0, 8,
                                      nullptr, nullptr, nullptr, nullptr, 0, slots);
    } else {
      // pairs p=1 (a=1) and p=2 (a=0) share b=2 inverses
      k_reduce<<<g32, 256, 0, stream>>>(bufA, 2, zz1, zz1, nzz1, nzz1, 9,
                                        zz0, zz0, nzz0, nzz0, 14, slots);
      k_reduce<<<g32, 256, 0, stream>>>(bufB, 2, z1, z1, nz1, nz1, 11,
                                        z0, z0, nz0, nz0, 16, slots);
      k_gemm<<<g32, 256, 0, stream>>>(bufA, bufA, nullptr, 0, 2,
                                      zz1, zz1, nzz1, nzz1, 10,
                                      zz0, zz0, nzz0, nzz0, 15, slots);
      k_gemm<<<g32, 256, 0, stream>>>(bufB, bufB, nullptr, 0, 2,
                                      z1, z1, nz1, nz1, 12,
                                      z0, z0, nz0, nz0, 17, slots);
      k_gemm<<<g32, 256, 0, stream>>>(bufA, bufT, nullptr, 0, 2,
                                      zz1, z1, nzz1, nz1, 13,
                                      zz0, z0, nzz0, nz0, 18, slots);
    }
  }
  k_combine<<<1, 1, 0, stream>>>(slots, out);
}

// Round 3
// 52094.708 us; speedup vs baseline: 1.0967x; 1.0967x over previous
//
#include <hip/hip_runtime.h>
#include <math.h>

// Problem constants (fixed by setup_inputs)
#define NN 4096      // N samples
#define DD 256       // flat endo dim (8 vars * 32)
#define NV 8         // vars
#define VD 32        // per-var dim
#define NB 128       // GJ block size
#define NBLK (NN/NB) // 32

// Output ownership mapping (bank-conflict-free):
//   rows  R(u) = ty*4 + 64*(u>>2) + (u&3),  u in [0,8)
//   cols  C(v) = tx*4 + 64*(v>>2) + (v&3),  v in [0,8)
#define RMAP(ty,u) ((ty)*4 + (((u)>>2)<<6) + ((u)&3))
#define CMAP(tx,v) ((tx)*4 + (((v)>>2)<<6) + ((v)&3))

// ---------------- helpers ----------------
__device__ __forceinline__ void block_atomic_add(float v, float* red, float* dst){
  #pragma unroll
  for (int off = 32; off > 0; off >>= 1) v += __shfl_down(v, off, 64);
  const int lane = threadIdx.x & 63;
  const int w = threadIdx.x >> 6;
  if (lane == 0) red[w] = v;
  __syncthreads();
  if (threadIdx.x == 0) atomicAdd(dst, red[0] + red[1] + red[2] + red[3]);
  __syncthreads();
}

// ---------------- small utility kernels ----------------
__global__ void k_zero(float* p, int n){
  int i = blockIdx.x * blockDim.x + threadIdx.x;
  if (i < n) p[i] = 0.f;
}

// per-(row,var) sums/norms
__global__ void k_norms(const float* __restrict__ z, const float* __restrict__ zz,
                        const float* __restrict__ stdn,
                        float* __restrict__ stdsq, float* __restrict__ zrs,
                        float* __restrict__ nzz, float* __restrict__ nz8){
  int t = blockIdx.x * blockDim.x + threadIdx.x;
  if (t >= NN * NV) return;
  int i = t / NV, v = t % NV;
  const float* zp  = z  + (size_t)i * DD + v * VD;
  const float* zzp = zz + (size_t)i * DD + v * VD;
  float s1 = 0.f, s2 = 0.f, s2z = 0.f;
  #pragma unroll
  for (int k = 0; k < VD; k++){
    float a = zp[k];  s1 += a; s2 += a * a;
    float b = zzp[k]; s2z += b * b;
  }
  zrs[(size_t)i * NV + v] = s1;
  nz8[(size_t)v * NN + i] = s2;
  nzz[(size_t)v * NN + i] = s2z;
  if (v == 0){
    float s = 0.f;
    #pragma unroll
    for (int u = 0; u < NV; u++){ float a = stdn[(size_t)i * NV + u]; s += a * a; }
    stdsq[i] = s;
  }
}

__global__ void k_rownorm(const float* __restrict__ nz8, float* __restrict__ nrmz){
  int i = blockIdx.x * blockDim.x + threadIdx.x;
  if (i < NN){
    float s = 0.f;
    #pragma unroll
    for (int v = 0; v < NV; v++) s += nz8[(size_t)v * NN + i];
    nrmz[i] = s;
  }
}

__global__ __launch_bounds__(256) void k_nll(const float* __restrict__ x,
                                             const float* __restrict__ xx,
                                             float* __restrict__ slots){
  __shared__ float red[4];
  float s = 0.f;
  const int total = NN * DD;
  for (int i = (blockIdx.x * 256 + threadIdx.x) * 4; i < total; i += gridDim.x * 256 * 4){
    float4 a = *(const float4*)(x + i);
    float4 b = *(const float4*)(xx + i);
    float d0 = b.x - a.x, d1 = b.y - a.y, d2 = b.z - a.z, d3 = b.w - a.w;
    s += d0*d0 + d1*d1 + d2*d2 + d3*d3;
  }
  block_atomic_add(s, red, slots + 3);
}

// ---------------- first (exo-free) MMD term ----------------
// Sqq = sum_ij exp(-||z_i - z_j||^2 / 2048), flat dim 256
__global__ __launch_bounds__(256) void k_sqq(const float* __restrict__ z,
                                             const float* __restrict__ nrm,
                                             float* __restrict__ slots){
  __shared__ float Xr[128 * 33];
  __shared__ float Xc[128 * 33];
  __shared__ float red[4];
  const int r0 = blockIdx.y * 128, c0 = blockIdx.x * 128;
  const int t = threadIdx.x;
  const int tx = t & 15, ty = t >> 4;
  const int lrow = t >> 1, lh = t & 1;
  float acc[8][8];
  #pragma unroll
  for (int u = 0; u < 8; u++)
    #pragma unroll
    for (int v = 0; v < 8; v++) acc[u][v] = 0.f;
  for (int ks = 0; ks < DD; ks += 32){
    const float* pr = z + (size_t)(r0 + lrow) * DD + ks + lh * 16;
    const float* pc = z + (size_t)(c0 + lrow) * DD + ks + lh * 16;
    float* dr = &Xr[lrow * 33 + lh * 16];
    float* dc = &Xc[lrow * 33 + lh * 16];
    #pragma unroll
    for (int u = 0; u < 4; u++){
      float4 a = ((const float4*)pr)[u];
      dr[4*u+0] = a.x; dr[4*u+1] = a.y; dr[4*u+2] = a.z; dr[4*u+3] = a.w;
      float4 b = ((const float4*)pc)[u];
      dc[4*u+0] = b.x; dc[4*u+1] = b.y; dc[4*u+2] = b.z; dc[4*u+3] = b.w;
    }
    __syncthreads();
    #pragma unroll
    for (int kk = 0; kk < 32; kk++){
      float a[8], b[8];
      #pragma unroll
      for (int u = 0; u < 8; u++) a[u] = Xr[RMAP(ty,u)*33 + kk];
      #pragma unroll
      for (int v = 0; v < 8; v++) b[v] = Xc[CMAP(tx,v)*33 + kk];
      #pragma unroll
      for (int u = 0; u < 8; u++)
        #pragma unroll
        for (int v = 0; v < 8; v++) acc[u][v] += a[u] * b[v];
    }
    __syncthreads();
  }
  float s = 0.f;
  #pragma unroll 1
  for (int u = 0; u < 8; u++){
    const float ni = nrm[r0 + RMAP(ty,u)];
    #pragma unroll 1
    for (int v = 0; v < 8; v++)
      s += __expf(-(ni + nrm[c0 + CMAP(tx,v)] - 2.f * acc[u][v]) * (1.f/2048.f));
  }
  block_atomic_add(s, red, slots + 0);
}

// Spp and Sqp via K=8 structure of the broadcast std_norm
__global__ __launch_bounds__(256) void k_spp_sqp(const float* __restrict__ stdn,
                                                 const float* __restrict__ stdsq,
                                                 const float* __restrict__ zrs,
                                                 const float* __restrict__ nrmz,
                                                 float* __restrict__ slots){
  __shared__ float sI[128*9], sJ[128*9], zI[128*9];
  __shared__ float qI[128], qJ[128], nI[128];
  __shared__ float red[4];
  const int r0 = blockIdx.y * 128, c0 = blockIdx.x * 128;
  const int t = threadIdx.x;
  if (t < 128){
    #pragma unroll
    for (int v = 0; v < 8; v++){
      sI[t*9+v] = stdn[(size_t)(r0+t)*NV + v];
      sJ[t*9+v] = stdn[(size_t)(c0+t)*NV + v];
      zI[t*9+v] = zrs[(size_t)(r0+t)*NV + v];
    }
    qI[t] = stdsq[r0+t]; qJ[t] = stdsq[c0+t]; nI[t] = nrmz[r0+t];
  }
  __syncthreads();
  const int tx = t & 15, ty = t >> 4;
  float spp = 0.f, sqp = 0.f;
  #pragma unroll 1
  for (int u = 0; u < 8; u++){
    int i = ty + 16*u;
    #pragma unroll 1
    for (int v = 0; v < 8; v++){
      int j = tx + 16*v;
      float dpp = 0.f, dqp = 0.f;
      #pragma unroll
      for (int k = 0; k < 8; k++){
        float sj = sJ[j*9+k];
        dpp += sI[i*9+k] * sj;
        dqp += zI[i*9+k] * sj;
      }
      spp += __expf(-(qI[i] + qJ[j] - 2.f*dpp) * (1.f/64.f));
      sqp += __expf(-(nI[i] + 32.f*qJ[j] - 2.f*dqp) * (1.f/2048.f));
    }
  }
  block_atomic_add(spp, red, slots + 1);
  block_atomic_add(sqp, red, slots + 2);
}

// ---------------- RBF Gram matrix build (K=32) ----------------
__global__ __launch_bounds__(256) void k_rbf(const float* __restrict__ Xr_,
                                             const float* __restrict__ Xc_,
                                             const float* __restrict__ nr,
                                             const float* __restrict__ nc,
                                             float lam, float* __restrict__ M){
  __shared__ float Xr[128 * 33];
  __shared__ float Xc[128 * 33];
  const int r0 = blockIdx.y * 128, c0 = blockIdx.x * 128;
  const int t = threadIdx.x;
  const int tx = t & 15, ty = t >> 4;
  const int lrow = t >> 1, lh = t & 1;
  {
    const float* pr = Xr_ + (size_t)(r0 + lrow) * DD + lh * 16;
    const float* pc = Xc_ + (size_t)(c0 + lrow) * DD + lh * 16;
    float* dr = &Xr[lrow * 33 + lh * 16];
    float* dc = &Xc[lrow * 33 + lh * 16];
    #pragma unroll
    for (int u = 0; u < 4; u++){
      float4 a = ((const float4*)pr)[u];
      dr[4*u+0]=a.x; dr[4*u+1]=a.y; dr[4*u+2]=a.z; dr[4*u+3]=a.w;
      float4 b = ((const float4*)pc)[u];
      dc[4*u+0]=b.x; dc[4*u+1]=b.y; dc[4*u+2]=b.z; dc[4*u+3]=b.w;
    }
  }
  __syncthreads();
  #pragma unroll 1
  for (int u = 0; u < 8; u++){
    const int gi = r0 + RMAP(ty,u);
    const float* xi = &Xr[RMAP(ty,u)*33];
    const float ni = nr[gi];
    float vals[8];
    #pragma unroll 1
    for (int v = 0; v < 8; v++){
      const int gj = c0 + CMAP(tx,v);
      const float* xj = &Xc[CMAP(tx,v)*33];
      float d = 0.f;
      #pragma unroll
      for (int k = 0; k < 32; k++) d += xi[k] * xj[k];
      float e = __expf(-(ni + nc[gj] - 2.f*d) * (1.f/32.f));
      if (gi == gj) e += lam;
      vals[v] = e;
    }
    float* pd = M + (size_t)gi * NN + c0 + tx*4;
    *(float4*)pd        = make_float4(vals[0], vals[1], vals[2], vals[3]);
    *(float4*)(pd + 64) = make_float4(vals[4], vals[5], vals[6], vals[7]);
  }
}

// ---------------- elementwise trace reduction: sum(L (on-the-fly) * M) ----------------
__global__ __launch_bounds__(256) void k_reduce(const float* __restrict__ M, int nepi,
    const float* e0xr, const float* e0xc, const float* e0nr, const float* e0nc, int s0,
    const float* e1xr, const float* e1xc, const float* e1nr, const float* e1nc, int s1,
    float* __restrict__ slots){
  __shared__ float sh[128 * 33 * 2];
  __shared__ float red[4];
  const int r0 = blockIdx.y * 128, c0 = blockIdx.x * 128;
  const int t = threadIdx.x;
  const int tx = t & 15, ty = t >> 4;
  const int lrow = t >> 1, lh = t & 1;
  float macc[8][8];
  #pragma unroll
  for (int u = 0; u < 8; u++){
    const float* pm = M + (size_t)(r0 + RMAP(ty,u)) * NN + c0 + tx*4;
    float4 m0 = *(const float4*)pm, m1 = *(const float4*)(pm + 64);
    macc[u][0]=m0.x; macc[u][1]=m0.y; macc[u][2]=m0.z; macc[u][3]=m0.w;
    macc[u][4]=m1.x; macc[u][5]=m1.y; macc[u][6]=m1.z; macc[u][7]=m1.w;
  }
  float* Xr = sh;
  float* Xc = sh + 128 * 33;
  for (int e = 0; e < nepi; e++){
    const float* xr = e ? e1xr : e0xr;
    const float* xc = e ? e1xc : e0xc;
    const float* nr = e ? e1nr : e0nr;
    const float* nc = e ? e1nc : e0nc;
    int slot = e ? s1 : s0;
    {
      const float* pr = xr + (size_t)(r0 + lrow) * DD + lh * 16;
      const float* pc = xc + (size_t)(c0 + lrow) * DD + lh * 16;
      float* dr = &Xr[lrow * 33 + lh * 16];
      float* dc = &Xc[lrow * 33 + lh * 16];
      #pragma unroll
      for (int u = 0; u < 4; u++){
        float4 a = ((const float4*)pr)[u];
        dr[4*u+0]=a.x; dr[4*u+1]=a.y; dr[4*u+2]=a.z; dr[4*u+3]=a.w;
        float4 b = ((const float4*)pc)[u];
        dc[4*u+0]=b.x; dc[4*u+1]=b.y; dc[4*u+2]=b.z; dc[4*u+3]=b.w;
      }
    }
    __syncthreads();
    float s = 0.f;
    #pragma unroll 1
    for (int u = 0; u < 8; u++){
      const float* xi = &Xr[RMAP(ty,u)*33];
      const float ni = nr[r0 + RMAP(ty,u)];
      #pragma unroll 1
      for (int v = 0; v < 8; v++){
        const float* xj = &Xc[CMAP(tx,v)*33];
        float d = 0.f;
        #pragma unroll
        for (int k = 0; k < 32; k++) d += xi[k] * xj[k];
        s += macc[u][v] * __expf(-(ni + nc[c0 + CMAP(tx,v)] - 2.f*d) * (1.f/32.f));
      }
    }
    block_atomic_add(s, red, slots + slot);
    __syncthreads();
  }
}

// ---------------- big fp32 GEMM, optional store, optional fused RBF-trace epilogues ----------------
// A staged [row][17] (scalar broadcast reads), B staged [kk][132] (ds_read_b128, 2-way=free).
__global__ __launch_bounds__(256) void k_gemm(const float* __restrict__ A,
                                              const float* __restrict__ B,
                                              float* __restrict__ D, int storeD, int nepi,
    const float* e0xr, const float* e0xc, const float* e0nr, const float* e0nc, int s0,
    const float* e1xr, const float* e1xc, const float* e1nr, const float* e1nc, int s1,
    float* __restrict__ slots){
  __shared__ float sh[128 * 33 * 2];
  __shared__ float red[4];
  const int r0 = blockIdx.y * 128, c0 = blockIdx.x * 128;
  const int t = threadIdx.x;
  const int tx = t & 15, ty = t >> 4;
  const int lrow = t >> 1, lh = t & 1;
  float acc[8][8];
  #pragma unroll
  for (int u = 0; u < 8; u++)
    #pragma unroll
    for (int v = 0; v < 8; v++) acc[u][v] = 0.f;

  float* As = sh;              // [128][17]
  float* Bs = sh + 128 * 17;   // [16][132]
  for (int ks = 0; ks < NN; ks += 16){
    {
      const float* pa = A + (size_t)(r0 + lrow) * NN + ks + lh * 8;
      float4 a0 = ((const float4*)pa)[0];
      float4 a1 = ((const float4*)pa)[1];
      float* da = &As[lrow * 17 + lh * 8];
      da[0]=a0.x; da[1]=a0.y; da[2]=a0.z; da[3]=a0.w;
      da[4]=a1.x; da[5]=a1.y; da[6]=a1.z; da[7]=a1.w;
      const int kkl = t >> 4, c8 = (t & 15) * 8;
      const float* pb = B + (size_t)(ks + kkl) * NN + c0 + c8;
      float4 b0 = ((const float4*)pb)[0];
      float4 b1 = ((const float4*)pb)[1];
      *(float4*)&Bs[kkl*132 + c8]     = b0;
      *(float4*)&Bs[kkl*132 + c8 + 4] = b1;
    }
    __syncthreads();
    #pragma unroll
    for (int kk = 0; kk < 16; kk++){
      float a[8], b[8];
      #pragma unroll
      for (int u = 0; u < 8; u++) a[u] = As[RMAP(ty,u)*17 + kk];
      float4 b0 = *(const float4*)&Bs[kk*132 + tx*4];
      float4 b1 = *(const float4*)&Bs[kk*132 + tx*4 + 64];
      b[0]=b0.x; b[1]=b0.y; b[2]=b0.z; b[3]=b0.w;
      b[4]=b1.x; b[5]=b1.y; b[6]=b1.z; b[7]=b1.w;
      #pragma unroll
      for (int u = 0; u < 8; u++)
        #pragma unroll
        for (int v = 0; v < 8; v++) acc[u][v] += a[u] * b[v];
    }
    __syncthreads();
  }
  if (storeD){
    #pragma unroll
    for (int u = 0; u < 8; u++){
      float* pd = D + (size_t)(r0 + RMAP(ty,u)) * NN + c0 + tx*4;
      *(float4*)pd        = make_float4(acc[u][0], acc[u][1], acc[u][2], acc[u][3]);
      *(float4*)(pd + 64) = make_float4(acc[u][4], acc[u][5], acc[u][6], acc[u][7]);
    }
  }
  float* Xr = sh;
  float* Xc = sh + 128 * 33;
  for (int e = 0; e < nepi; e++){
    const float* xr = e ? e1xr : e0xr;
    const float* xc = e ? e1xc : e0xc;
    const float* nr = e ? e1nr : e0nr;
    const float* nc = e ? e1nc : e0nc;
    int slot = e ? s1 : s0;
    {
      const float* pr = xr + (size_t)(r0 + lrow) * DD + lh * 16;
      const float* pc = xc + (size_t)(c0 + lrow) * DD + lh * 16;
      float* dr = &Xr[lrow * 33 + lh * 16];
      float* dc = &Xc[lrow * 33 + lh * 16];
      #pragma unroll
      for (int u = 0; u < 4; u++){
        float4 a = ((const float4*)pr)[u];
        dr[4*u+0]=a.x; dr[4*u+1]=a.y; dr[4*u+2]=a.z; dr[4*u+3]=a.w;
        float4 b = ((const float4*)pc)[u];
        dc[4*u+0]=b.x; dc[4*u+1]=b.y; dc[4*u+2]=b.z; dc[4*u+3]=b.w;
      }
    }
    __syncthreads();
    float s = 0.f;
    #pragma unroll 1
    for (int u = 0; u < 8; u++){
      const float* xi = &Xr[RMAP(ty,u)*33];
      const float ni = nr[r0 + RMAP(ty,u)];
      #pragma unroll 1
      for (int v = 0; v < 8; v++){
        const float* xj = &Xc[CMAP(tx,v)*33];
        float d = 0.f;
        #pragma unroll
        for (int k = 0; k < 32; k++) d += xi[k] * xj[k];
        s += acc[u][v] * __expf(-(ni + nc[c0 + CMAP(tx,v)] - 2.f*d) * (1.f/32.f));
      }
    }
    block_atomic_add(s, red, slots + slot);
    __syncthreads();
  }
}

// ---------------- U = Kqp(on-the-fly) @ B  (saves materializing Kqp) ----------------
__global__ __launch_bounds__(256) void k_gemm_kqpB(
    const float* __restrict__ Xq, const float* __restrict__ nq,
    const float* __restrict__ Xp, const float* __restrict__ np_,
    const float* __restrict__ B, float* __restrict__ U){
  __shared__ float Q[128 * 33];   // row-side exo vectors (loaded once)
  __shared__ float Zk[16 * 33];   // k-side exo vectors for current k block
  __shared__ float As[128 * 17];  // generated Kqp tile
  __shared__ float Bs[16 * 132];
  const int r0 = blockIdx.y * 128, c0 = blockIdx.x * 128;
  const int t = threadIdx.x;
  const int tx = t & 15, ty = t >> 4;
  const int lrow = t >> 1, lh = t & 1;
  {
    const float* pr = Xq + (size_t)(r0 + lrow) * DD + lh * 16;
    float* dr = &Q[lrow * 33 + lh * 16];
    #pragma unroll
    for (int u = 0; u < 4; u++){
      float4 a = ((const float4*)pr)[u];
      dr[4*u+0]=a.x; dr[4*u+1]=a.y; dr[4*u+2]=a.z; dr[4*u+3]=a.w;
    }
  }
  const int arow = t >> 1, acb = (t & 1) * 8;   // A-tile generation assignment
  const float nqr = nq[r0 + arow];
  float acc[8][8];
  #pragma unroll
  for (int u = 0; u < 8; u++)
    #pragma unroll
    for (int v = 0; v < 8; v++) acc[u][v] = 0.f;
  for (int ks = 0; ks < NN; ks += 16){
    if (t < 128){
      const int zr = t >> 3, zs = (t & 7) * 4;
      float4 a = *(const float4*)(Xp + (size_t)(ks + zr) * DD + zs);
      float* d = &Zk[zr * 33 + zs];
      d[0]=a.x; d[1]=a.y; d[2]=a.z; d[3]=a.w;
    }
    {
      const int kkl = t >> 4, c8 = (t & 15) * 8;
      const float* pb = B + (size_t)(ks + kkl) * NN + c0 + c8;
      float4 b0 = ((const float4*)pb)[0];
      float4 b1 = ((const float4*)pb)[1];
      *(float4*)&Bs[kkl*132 + c8]     = b0;
      *(float4*)&Bs[kkl*132 + c8 + 4] = b1;
    }
    __syncthreads();
    {
      const float* qi = &Q[arow * 33];
      #pragma unroll
      for (int j = 0; j < 8; j++){
        const int c = acb + j;
        const float* pj = &Zk[c * 33];
        float d = 0.f;
        #pragma unroll
        for (int k = 0; k < 32; k++) d += qi[k] * pj[k];
        As[arow * 17 + c] = __expf(-(nqr + np_[ks + c] - 2.f*d) * (1.f/32.f));
      }
    }
    __syncthreads();
    #pragma unroll
    for (int kk = 0; kk < 16; kk++){
      float a[8], b[8];
      #pragma unroll
      for (int u = 0; u < 8; u++) a[u] = As[RMAP(ty,u)*17 + kk];
      float4 b0 = *(const float4*)&Bs[kk*132 + tx*4];
      float4 b1 = *(const float4*)&Bs[kk*132 + tx*4 + 64];
      b[0]=b0.x; b[1]=b0.y; b[2]=b0.z; b[3]=b0.w;
      b[4]=b1.x; b[5]=b1.y; b[6]=b1.z; b[7]=b1.w;
      #pragma unroll
      for (int u = 0; u < 8; u++)
        #pragma unroll
        for (int v = 0; v < 8; v++) acc[u][v] += a[u] * b[v];
    }
    __syncthreads();
  }
  #pragma unroll
  for (int u = 0; u < 8; u++){
    float* pd = U + (size_t)(r0 + RMAP(ty,u)) * NN + c0 + tx*4;
    *(float4*)pd        = make_float4(acc[u][0], acc[u][1], acc[u][2], acc[u][3]);
    *(float4*)(pd + 64) = make_float4(acc[u][4], acc[u][5], acc[u][6], acc[u][7]);
  }
}

// ---------------- blocked Gauss-Jordan SPD inverse (batched x2 via blockIdx) ----------------
__global__ __launch_bounds__(1024) void k_gj_diag(float* __restrict__ M0, float* __restrict__ M1,
                                                  float* __restrict__ Pbuf, int kb){
  float* M = blockIdx.x ? M1 : M0;
  float* P = Pbuf + (size_t)blockIdx.x * NB * NB;
  __shared__ float rowbuf[NB];
  __shared__ float colbuf[NB];
  __shared__ float pivsh;
  const int t = threadIdx.x;
  const int r = t >> 3, g = t & 7;   // row 0..127, col-group 0..7 (cols g+8j)
  const int k0 = kb * NB;
  float reg[16];
  #pragma unroll
  for (int j = 0; j < 16; j++) reg[j] = M[(size_t)(k0 + r) * NN + k0 + g + 8*j];
  __syncthreads();
  for (int jj = 0; jj < NB; jj++){
    if (r == jj && g == (jj & 7)) pivsh = reg[jj >> 3];
    __syncthreads();
    const float p = 1.0f / pivsh;
    if (r == jj){
      #pragma unroll
      for (int j = 0; j < 16; j++){
        int c = g + 8*j;
        float val = (c == jj) ? p : reg[j] * p;
        reg[j] = val;
        rowbuf[c] = val;
      }
    } else if (g == (jj & 7)){
      colbuf[r] = reg[jj >> 3];
    }
    __syncthreads();
    if (r != jj){
      const float f = colbuf[r];
      #pragma unroll
      for (int j = 0; j < 16; j++){
        int c = g + 8*j;
        reg[j] = (c == jj) ? (-f * p) : (reg[j] - f * rowbuf[c]);
      }
    }
    __syncthreads();
  }
  #pragma unroll
  for (int j = 0; j < 16; j++) P[r * NB + g + 8*j] = reg[j];
}

// Panel: T = P @ M[k-block row, :]; C = copy of M[:, k-block col]
__global__ __launch_bounds__(256) void k_gj_panel(float* __restrict__ M0, float* __restrict__ M1,
                                                  const float* __restrict__ Pbuf,
                                                  float* __restrict__ Tbuf, float* __restrict__ Cbuf,
                                                  int kb){
  const int mat = blockIdx.y;
  float* M = mat ? M1 : M0;
  const float* P = Pbuf + (size_t)mat * NB * NB;
  float* T = Tbuf + (size_t)mat * NB * NN;
  float* C = Cbuf + (size_t)mat * NN * NB;
  const int jb = blockIdx.x;
  const int k0 = kb * NB, j0 = jb * NB;
  const int t = threadIdx.x;
  {
    const int row = t >> 1, half = (t & 1) * 64;
    const float* src = M + (size_t)(j0 + row) * NN + k0 + half;
    float* dst = C + (size_t)(j0 + row) * NB + half;
    #pragma unroll
    for (int u = 0; u < 16; u++) ((float4*)dst)[u] = ((const float4*)src)[u];
  }
  __shared__ float As[128 * 17];
  __shared__ float Bs[16 * 132];
  const int tx = t & 15, ty = t >> 4;
  const int lrow = t >> 1, lh = t & 1;
  float acc[8][8];
  #pragma unroll
  for (int u = 0; u < 8; u++)
    #pragma unroll
    for (int v = 0; v < 8; v++) acc[u][v] = 0.f;
  for (int ks = 0; ks < NB; ks += 16){
    {
      const float* pa = P + (size_t)lrow * NB + ks + lh * 8;
      float4 a0 = ((const float4*)pa)[0];
      float4 a1 = ((const float4*)pa)[1];
      float* da = &As[lrow * 17 + lh * 8];
      da[0]=a0.x; da[1]=a0.y; da[2]=a0.z; da[3]=a0.w;
      da[4]=a1.x; da[5]=a1.y; da[6]=a1.z; da[7]=a1.w;
      const int kkl = t >> 4, c8 = (t & 15) * 8;
      const float* pb = M + (size_t)(k0 + ks + kkl) * NN + j0 + c8;
      float4 b0 = ((const float4*)pb)[0];
      float4 b1 = ((const float4*)pb)[1];
      *(float4*)&Bs[kkl*132 + c8]     = b0;
      *(float4*)&Bs[kkl*132 + c8 + 4] = b1;
    }
    __syncthreads();
    #pragma unroll
    for (int kk = 0; kk < 16; kk++){
      float a[8], b[8];
      #pragma unroll
      for (int u = 0; u < 8; u++) a[u] = As[RMAP(ty,u)*17 + kk];
      float4 b0 = *(const float4*)&Bs[kk*132 + tx*4];
      float4 b1 = *(const float4*)&Bs[kk*132 + tx*4 + 64];
      b[0]=b0.x; b[1]=b0.y; b[2]=b0.z; b[3]=b0.w;
      b[4]=b1.x; b[5]=b1.y; b[6]=b1.z; b[7]=b1.w;
      #pragma unroll
      for (int u = 0; u < 8; u++)
        #pragma unroll
        for (int v = 0; v < 8; v++) acc[u][v] += a[u] * b[v];
    }
    __syncthreads();
  }
  #pragma unroll
  for (int u = 0; u < 8; u++){
    float* pd = T + (size_t)RMAP(ty,u) * NN + j0 + tx*4;
    *(float4*)pd        = make_float4(acc[u][0], acc[u][1], acc[u][2], acc[u][3]);
    *(float4*)(pd + 64) = make_float4(acc[u][4], acc[u][5], acc[u][6], acc[u][7]);
  }
}

// Trailing update + panel writeback
__global__ __launch_bounds__(256) void k_gj_update(float* __restrict__ M0, float* __restrict__ M1,
                                                   const float* __restrict__ Pbuf,
                                                   const float* __restrict__ Tbuf,
                                                   const float* __restrict__ Cbuf, int kb){
  __shared__ float As[128 * 17];
  __shared__ float Bs[16 * 132];
  const int mat = blockIdx.z;
  float* M = mat ? M1 : M0;
  const float* P = Pbuf + (size_t)mat * NB * NB;
  const float* T = Tbuf + (size_t)mat * NB * NN;
  const float* C = Cbuf + (size_t)mat * NN * NB;
  const int jb = blockIdx.x, ib = blockIdx.y;
  const int k0 = kb * NB, i0 = ib * NB, j0 = jb * NB;
  const int t = threadIdx.x;
  if (ib == kb){
    const int row = t >> 1, half = (t & 1) * 64;
    float* dst = M + (size_t)(k0 + row) * NN + j0 + half;
    if (jb == kb){
      const float* src = P + (size_t)row * NB + half;
      #pragma unroll
      for (int u = 0; u < 16; u++) ((float4*)dst)[u] = ((const float4*)src)[u];
    } else {
      const float* src = T + (size_t)row * NN + j0 + half;
      #pragma unroll
      for (int u = 0; u < 16; u++) ((float4*)dst)[u] = ((const float4*)src)[u];
    }
    return;
  }
  const int tx = t & 15, ty = t >> 4;
  const int lrow = t >> 1, lh = t & 1;
  float acc[8][8];
  #pragma unroll
  for (int u = 0; u < 8; u++)
    #pragma unroll
    for (int v = 0; v < 8; v++) acc[u][v] = 0.f;
  const float* Bbase = (jb == kb) ? P : (T + j0);
  const size_t ldb = (jb == kb) ? (size_t)NB : (size_t)NN;
  for (int ks = 0; ks < NB; ks += 16){
    {
      const float* pa = C + (size_t)(i0 + lrow) * NB + ks + lh * 8;
      float4 a0 = ((const float4*)pa)[0];
      float4 a1 = ((const float4*)pa)[1];
      float* da = &As[lrow * 17 + lh * 8];
      da[0]=a0.x; da[1]=a0.y; da[2]=a0.z; da[3]=a0.w;
      da[4]=a1.x; da[5]=a1.y; da[6]=a1.z; da[7]=a1.w;
      const int kkl = t >> 4, c8 = (t & 15) * 8;
      const float* pb = Bbase + (size_t)(ks + kkl) * ldb + c8;
      float4 b0 = ((const float4*)pb)[0];
      float4 b1 = ((const float4*)pb)[1];
      *(float4*)&Bs[kkl*132 + c8]     = b0;
      *(float4*)&Bs[kkl*132 + c8 + 4] = b1;
    }
    __syncthreads();
    #pragma unroll
    for (int kk = 0; kk < 16; kk++){
      float a[8], b[8];
      #pragma unroll
      for (int u = 0; u < 8; u++) a[u] = As[RMAP(ty,u)*17 + kk];
      float4 b0 = *(const float4*)&Bs[kk*132 + tx*4];
      float4 b1 = *(const float4*)&Bs[kk*132 + tx*4 + 64];
      b[0]=b0.x; b[1]=b0.y; b[2]=b0.z; b[3]=b0.w;
      b[4]=b1.x; b[5]=b1.y; b[6]=b1.z; b[7]=b1.w;
      #pragma unroll
      for (int u = 0; u < 8; u++)
        #pragma unroll
        for (int v = 0; v < 8; v++) acc[u][v] += a[u] * b[v];
    }
    __syncthreads();
  }
  if (jb == kb){
    #pragma unroll
    for (int u = 0; u < 8; u++){
      float* pd = M + (size_t)(i0 + RMAP(ty,u)) * NN + k0 + tx*4;
      *(float4*)pd        = make_float4(-acc[u][0], -acc[u][1], -acc[u][2], -acc[u][3]);
      *(float4*)(pd + 64) = make_float4(-acc[u][4], -acc[u][5], -acc[u][6], -acc[u][7]);
    }
  } else {
    #pragma unroll
    for (int u = 0; u < 8; u++){
      float* pd = M + (size_t)(i0 + RMAP(ty,u)) * NN + j0 + tx*4;
      float4 m0 = *(const float4*)pd, m1 = *(const float4*)(pd + 64);
      m0.x -= acc[u][0]; m0.y -= acc[u][1]; m0.z -= acc[u][2]; m0.w -= acc[u][3];
      m1.x -= acc[u][4]; m1.y -= acc[u][5]; m1.z -= acc[u][6]; m1.w -= acc[u][7];
      *(float4*)pd        = m0;
      *(float4*)(pd + 64) = m1;
    }
  }
}

// ---------------- final combine ----------------
__global__ void k_combine(const float* __restrict__ slots, float* __restrict__ out){
  if (threadIdx.x == 0 && blockIdx.x == 0){
    const double invN2 = 1.0 / ((double)NN * (double)NN);
    double term1 = ((double)slots[0] + (double)slots[1] - 2.0 * (double)slots[2]) * invN2;
    double pairs = 0.0;
    for (int p = 0; p < 3; p++){
      const float* s = slots + 4 + 5 * p;
      pairs += ((double)s[0] - 0.2 * (double)s[1] + (double)s[2] - 0.2 * (double)s[3] - 2.0 * (double)s[4]);
    }
    out[0] = (float)(1.0 * term1 + 500.0 * pairs * invN2);
    out[1] = (float)((double)slots[3] / (2.0 * (double)NN));
  }
}

// ---------------- host ----------------
extern "C" void kernel_launch(void* const* d_in, const int* in_sizes, int n_in,
                              void* d_out, int out_size, void* d_ws, size_t ws_size,
                              hipStream_t stream){
  const float* x    = (const float*)d_in[0];
  const float* z    = (const float*)d_in[1];
  const float* zz   = (const float*)d_in[2];
  const float* xx   = (const float*)d_in[3];
  const float* stdn = (const float*)d_in[4];
  float* out = (float*)d_out;
  float* ws  = (float*)d_ws;

  const size_t NN2 = (size_t)NN * NN;
  float* bufA = ws;                       // Kq -> A = Kq^-1
  float* bufB = bufA + NN2;               // Kp -> B = Kp^-1
  float* bufT = bufB + NN2;               // U = Kqp @ B (Kqp generated on the fly)
  float* Tb   = bufT + NN2;               // 2 * NB * NN
  float* Cb   = Tb + 2 * (size_t)NB * NN; // 2 * NN * NB
  float* Pb   = Cb + 2 * (size_t)NB * NN; // 2 * NB * NB
  float* slots= Pb + 2 * (size_t)NB * NB; // 32
  float* stdsq= slots + 32;               // NN
  float* zrs  = stdsq + NN;               // NN*NV
  float* nzz  = zrs + (size_t)NN * NV;    // NV*NN (zz per-var sq norms)
  float* nz8  = nzz + (size_t)NV * NN;    // NV*NN (z per-var sq norms)
  float* nrmz = nz8 + (size_t)NV * NN;    // NN (z flat-256 sq norms)

  dim3 g32(NBLK, NBLK);

  k_zero<<<1, 64, 0, stream>>>(slots, 32);
  k_norms<<<(NN * NV) / 256, 256, 0, stream>>>(z, zz, stdn, stdsq, zrs, nzz, nz8);
  k_rownorm<<<NN / 256, 256, 0, stream>>>(nz8, nrmz);
  k_nll<<<1024, 256, 0, stream>>>(x, xx, slots);
  k_sqq<<<g32, 256, 0, stream>>>(z, nrmz, slots);
  k_spp_sqp<<<g32, 256, 0, stream>>>(stdn, stdsq, zrs, nrmz, slots);

  const float* zz0 = zz;            const float* z0 = z;
  const float* zz1 = zz + VD;       const float* z1 = z + VD;
  const float* nzz0 = nzz;          const float* nz0 = nz8;
  const float* nzz1 = nzz + NN;     const float* nz1 = nz8 + NN;

  for (int b = 1; b <= 2; b++){
    k_rbf<<<g32, 256, 0, stream>>>(zz + b*VD, zz + b*VD, nzz + (size_t)b*NN, nzz + (size_t)b*NN, 0.2f, bufA);
    k_rbf<<<g32, 256, 0, stream>>>(z + b*VD,  z + b*VD,  nz8 + (size_t)b*NN, nz8 + (size_t)b*NN, 0.2f, bufB);
    for (int kb = 0; kb < NBLK; kb++){
      k_gj_diag<<<2, 1024, 0, stream>>>(bufA, bufB, Pb, kb);
      k_gj_panel<<<dim3(NBLK, 2), 256, 0, stream>>>(bufA, bufB, Pb, Tb, Cb, kb);
      k_gj_update<<<dim3(NBLK, NBLK, 2), 256, 0, stream>>>(bufA, bufB, Pb, Tb, Cb, kb);
    }
    k_gemm_kqpB<<<g32, 256, 0, stream>>>(zz + b*VD, nzz + (size_t)b*NN,
                                         z + b*VD,  nz8 + (size_t)b*NN, bufB, bufT);
    if (b == 1){
      k_reduce<<<g32, 256, 0, stream>>>(bufA, 1, zz0, zz0, nzz0, nzz0, 4,
                                        nullptr, nullptr, nullptr, nullptr, 0, slots);
      k_reduce<<<g32, 256, 0, stream>>>(bufB, 1, z0, z0, nz0, nz0, 6,
                                        nullptr, nullptr, nullptr, nullptr, 0, slots);
      k_gemm<<<g32, 256, 0, stream>>>(bufA, bufA, nullptr, 0, 1,
                                      zz0, zz0, nzz0, nzz0, 5,
                                      nullptr, nullptr, nullptr, nullptr, 0, slots);
      k_gemm<<<g32, 256, 0, stream>>>(bufB, bufB, nullptr, 0, 1,
                                      z0, z0, nz0, nz0, 7,
                                      nullptr, nullptr, nullptr, nullptr, 0, slots);
      k_gemm<<<g32, 256, 0, stream>>>(bufA, bufT, nullptr, 0, 1,
                                      zz0, z0, nzz0, nz0, 8,
                                      nullptr, nullptr, nullptr, nullptr, 0, slots);
    } else {
      k_reduce<<<g32, 256, 0, stream>>>(bufA, 2, zz1, zz1, nzz1, nzz1, 9,
                                        zz0, zz0, nzz0, nzz0, 14, slots);
      k_reduce<<<g32, 256, 0, stream>>>(bufB, 2, z1, z1, nz1, nz1, 11,
                                        z0, z0, nz0, nz0, 16, slots);
      k_gemm<<<g32, 256, 0, stream>>>(bufA, bufA, nullptr, 0, 2,
                                      zz1, zz1, nzz1, nzz1, 10,
                                      zz0, zz0, nzz0, nzz0, 15, slots);
      k_gemm<<<g32, 256, 0, stream>>>(bufB, bufB, nullptr, 0, 2,
                                      z1, z1, nz1, nz1, 12,
                                      z0, z0, nz0, nz0, 17, slots);
      k_gemm<<<g32, 256, 0, stream>>>(bufA, bufT, nullptr, 0, 2,
                                      zz1, z1, nzz1, nz1, 13,
                                      zz0, z0, nzz0, nz0, 18, slots);
    }
  }
  k_combine<<<1, 1, 0, stream>>>(slots, out);
}